// Round 1
// baseline (1646.420 us; speedup 1.0000x reference)
//
#include <hip/hip_runtime.h>
#include <math.h>

#define BB 4
#define SS 2048
#define DD 768
#define HH 8
#define DHD 96
#define SEP_ID 102

static __device__ __forceinline__ float gelu_tanh(float x) {
  float x3 = x * x * x;
  float t = tanhf(0.7978845608028654f * (x + 0.044715f * x3));
  return 0.5f * x * (1.0f + t);
}

// ---------------- segment discovery ----------------
__global__ void seg_kernel(const int* __restrict__ ids, int* __restrict__ seg) {
  int b = blockIdx.x;
  const int* row = ids + (size_t)b * SS;
  __shared__ int s1[256], s2[256];
  int m1 = SS, m2 = SS;  // two smallest sep indices
  for (int i = threadIdx.x; i < SS; i += 256) {
    if (row[i] == SEP_ID) {
      if (i < m1) { m2 = m1; m1 = i; }
      else if (i < m2) { m2 = i; }
    }
  }
  s1[threadIdx.x] = m1; s2[threadIdx.x] = m2;
  __syncthreads();
  for (int off = 128; off > 0; off >>= 1) {
    if (threadIdx.x < off) {
      int a1 = s1[threadIdx.x], a2 = s2[threadIdx.x];
      int b1 = s1[threadIdx.x + off], b2 = s2[threadIdx.x + off];
      int n1 = min(a1, b1);
      int n2 = min(max(a1, b1), min(a2, b2));
      s1[threadIdx.x] = n1; s2[threadIdx.x] = n2;
    }
    __syncthreads();
  }
  if (threadIdx.x == 0) {
    int first = s1[0], second = s2[0];
    bool has2 = (second < SS);
    int mid = SS / 2;
    int src_end = has2 ? first : mid;
    int hyp_lo = has2 ? (first + 1) : mid;
    int hyp_hi = has2 ? second : (SS - 1);
    int n_src = src_end - 1;       // keys are [1, src_end)
    int n_hyp = hyp_hi - hyp_lo;
    int valid = (n_src > 0 && n_hyp > 0) ? 1 : 0;
    if (!valid) { src_end = 1; hyp_lo = 0; hyp_hi = 0; }
    seg[b * 4 + 0] = src_end;
    seg[b * 4 + 1] = hyp_lo;
    seg[b * 4 + 2] = hyp_hi;
    seg[b * 4 + 3] = valid;
  }
}

// ---------------- out = x ----------------
__global__ void copy_x(const float* __restrict__ x, float* __restrict__ out, int n4) {
  int i = blockIdx.x * blockDim.x + threadIdx.x;
  int stride = gridDim.x * blockDim.x;
  const float4* xi = (const float4*)x;
  float4* oi = (float4*)out;
  for (; i < n4; i += stride) oi[i] = xi[i];
}

// ---------------- row-range GEMM: C[rows,768] = A[rows,768] @ W[768,768] + bias ----------------
// sel==0: src rows [1, seg[0]) ; sel==1: hyp rows [seg[1], seg[2])
__global__ __launch_bounds__(256) void gemm_rows(
    const float* __restrict__ A, const float* __restrict__ W,
    const float* __restrict__ bias, float* __restrict__ C,
    const int* __restrict__ seg, int sel, int gelu) {
  int b = blockIdx.z;
  int lo = (sel == 0) ? 1 : seg[b * 4 + 1];
  int hi = (sel == 0) ? seg[b * 4 + 0] : seg[b * 4 + 2];
  int row0 = lo + (int)blockIdx.y * 64;
  if (row0 >= hi) return;
  int col0 = blockIdx.x * 64;

  __shared__ float As[16][68];  // [k][m], padded
  __shared__ float Bs[16][64];  // [k][n]
  int tid = threadIdx.x;
  int tx = tid & 15, ty = tid >> 4;
  float acc[4][4] = {};

  int am = tid >> 2, ak = (tid & 3) * 4;   // A: row am, k-offset ak (float4)
  int bk = tid >> 4, bc = (tid & 15) * 4;  // B: k row bk, col bc (float4)
  const float* Arow = A + ((size_t)(b * SS + row0 + am)) * DD;
  bool arow_ok = (row0 + am) < hi;

  for (int k0 = 0; k0 < DD; k0 += 16) {
    float4 av = make_float4(0.f, 0.f, 0.f, 0.f);
    if (arow_ok) av = *(const float4*)(Arow + k0 + ak);
    As[ak + 0][am] = av.x; As[ak + 1][am] = av.y;
    As[ak + 2][am] = av.z; As[ak + 3][am] = av.w;
    float4 bv = *(const float4*)(W + (size_t)(k0 + bk) * DD + col0 + bc);
    *(float4*)&Bs[bk][bc] = bv;
    __syncthreads();
#pragma unroll
    for (int kk = 0; kk < 16; ++kk) {
      float4 a = *(const float4*)&As[kk][ty * 4];
      float4 bq = *(const float4*)&Bs[kk][tx * 4];
      float ar[4] = {a.x, a.y, a.z, a.w};
      float br[4] = {bq.x, bq.y, bq.z, bq.w};
#pragma unroll
      for (int i = 0; i < 4; ++i)
#pragma unroll
        for (int j = 0; j < 4; ++j) acc[i][j] += ar[i] * br[j];
    }
    __syncthreads();
  }
  float bs[4];
#pragma unroll
  for (int j = 0; j < 4; ++j) bs[j] = bias[col0 + tx * 4 + j];
#pragma unroll
  for (int i = 0; i < 4; ++i) {
    int row = row0 + ty * 4 + i;
    if (row < hi) {
      float* cp = C + ((size_t)(b * SS + row)) * DD + col0 + tx * 4;
#pragma unroll
      for (int j = 0; j < 4; ++j) {
        float v = acc[i][j] + bs[j];
        if (gelu) v = gelu_tanh(v);
        cp[j] = v;
      }
    }
  }
}

// ---------------- attention: one block per (b, q); 4 waves x 2 heads ----------------
__global__ __launch_bounds__(256) void attn_kernel(
    const float* __restrict__ Q, const float* __restrict__ K, const float* __restrict__ V,
    float* __restrict__ ctx, const int* __restrict__ seg) {
  int b = blockIdx.y;
  int q = blockIdx.x;
  int hyp_lo = seg[b * 4 + 1], hyp_hi = seg[b * 4 + 2];
  if (q < hyp_lo || q >= hyp_hi) return;
  int src_hi = seg[b * 4 + 0];

  __shared__ float q_lds[DD];
  __shared__ float sc[4][256];
  int tid = threadIdx.x;
  for (int i = tid; i < DD; i += 256) q_lds[i] = Q[((size_t)(b * SS + q)) * DD + i];
  __syncthreads();

  int w = tid >> 6, lane = tid & 63;
  const float rs = 0.1020620726159658f;  // 1/sqrt(96)

  for (int hh = 0; hh < 2; ++hh) {
    int h = w * 2 + hh;
    const float4* qh = (const float4*)&q_lds[h * DHD];
    float m = -1e30f, l = 0.f, acc0 = 0.f, acc1 = 0.f;

    for (int c0 = 1; c0 < src_hi; c0 += 256) {
      int nk = min(256, src_hi - c0);
      float s[4];
      float cmax = -1e30f;
#pragma unroll
      for (int ii = 0; ii < 4; ++ii) {
        int j = c0 + ii * 64 + lane;
        float sv = -1e30f;
        if (j < src_hi) {
          const float4* kp = (const float4*)(K + ((size_t)(b * SS + j)) * DD + h * DHD);
          float a = 0.f;
#pragma unroll
          for (int d4 = 0; d4 < 24; ++d4) {
            float4 kv = kp[d4];
            float4 qv = qh[d4];
            a += qv.x * kv.x + qv.y * kv.y + qv.z * kv.z + qv.w * kv.w;
          }
          sv = a * rs;
        }
        s[ii] = sv;
        cmax = fmaxf(cmax, sv);
      }
#pragma unroll
      for (int off = 32; off > 0; off >>= 1)
        cmax = fmaxf(cmax, __shfl_xor(cmax, off));
      float m_new = fmaxf(m, cmax);
      float scale = __expf(m - m_new);
      acc0 *= scale; acc1 *= scale; l *= scale;
      m = m_new;
#pragma unroll
      for (int ii = 0; ii < 4; ++ii) {
        int idx = ii * 64 + lane;
        float p = (idx < nk) ? __expf(s[ii] - m) : 0.f;
        sc[w][idx] = p;
        l += p;
      }
      __syncthreads();  // uniform trip counts across all 4 waves
      for (int idx = 0; idx < nk; ++idx) {
        float p = sc[w][idx];
        const float* vp = V + ((size_t)(b * SS + c0 + idx)) * DD + h * DHD;
        acc0 += p * vp[lane];
        if (lane < 32) acc1 += p * vp[64 + lane];
      }
      __syncthreads();
    }
    float lt = l;
#pragma unroll
    for (int off = 32; off > 0; off >>= 1) lt += __shfl_xor(lt, off);
    float inv = 1.f / lt;
    float* cp = ctx + ((size_t)(b * SS + q)) * DD + h * DHD;
    cp[lane] = acc0 * inv;
    if (lane < 32) cp[64 + lane] = acc1 * inv;
  }
}

// ---------------- block reduction helper ----------------
__device__ __forceinline__ float block_sum(float v, float* sbuf) {
#pragma unroll
  for (int off = 32; off > 0; off >>= 1) v += __shfl_xor(v, off);
  int lane = threadIdx.x & 63, w = threadIdx.x >> 6;
  __syncthreads();
  if (lane == 0) sbuf[w] = v;
  __syncthreads();
  return sbuf[0] + sbuf[1] + sbuf[2] + sbuf[3];
}

// ---------------- x1 = LN(x + mha) over hyp rows ----------------
__global__ __launch_bounds__(256) void ln_residual(
    const float* __restrict__ X, const float* __restrict__ Yin,
    const float* __restrict__ g, const float* __restrict__ bta,
    float* __restrict__ Out, const int* __restrict__ seg) {
  int b = blockIdx.y, row = blockIdx.x;
  if (row < seg[b * 4 + 1] || row >= seg[b * 4 + 2]) return;
  __shared__ float sbuf[4];
  size_t base = ((size_t)(b * SS + row)) * DD;
  int tid = threadIdx.x;
  float v[3];
  float sum = 0.f;
#pragma unroll
  for (int r = 0; r < 3; ++r) {
    int i = tid + r * 256;
    v[r] = X[base + i] + Yin[base + i];
    sum += v[r];
  }
  float mean = block_sum(sum, sbuf) * (1.f / DD);
  float vs = 0.f;
#pragma unroll
  for (int r = 0; r < 3; ++r) { float d = v[r] - mean; vs += d * d; }
  float var = block_sum(vs, sbuf) * (1.f / DD);
  float inv = rsqrtf(var + 1e-5f);
#pragma unroll
  for (int r = 0; r < 3; ++r) {
    int i = tid + r * 256;
    Out[base + i] = (v[r] - mean) * inv * g[i] + bta[i];
  }
}

// ---------------- x2 = LN(x1 + t2); diff = LN(x2 - x); out = x + diff (hyp rows) ----------------
__global__ __launch_bounds__(256) void ln2_diff_scatter(
    const float* __restrict__ X, const float* __restrict__ X1, const float* __restrict__ T2,
    const float* __restrict__ g2, const float* __restrict__ b2,
    const float* __restrict__ gd, const float* __restrict__ bd,
    float* __restrict__ Out, const int* __restrict__ seg) {
  int b = blockIdx.y, row = blockIdx.x;
  if (row < seg[b * 4 + 1] || row >= seg[b * 4 + 2]) return;
  __shared__ float sbuf[4];
  size_t base = ((size_t)(b * SS + row)) * DD;
  int tid = threadIdx.x;
  float y[3], xv[3];
  float sum = 0.f;
#pragma unroll
  for (int r = 0; r < 3; ++r) {
    int i = tid + r * 256;
    y[r] = X1[base + i] + T2[base + i];
    xv[r] = X[base + i];
    sum += y[r];
  }
  float mean = block_sum(sum, sbuf) * (1.f / DD);
  float vs = 0.f;
#pragma unroll
  for (int r = 0; r < 3; ++r) { float d = y[r] - mean; vs += d * d; }
  float var = block_sum(vs, sbuf) * (1.f / DD);
  float inv = rsqrtf(var + 1e-5f);
  float z[3];
  float sum2 = 0.f;
#pragma unroll
  for (int r = 0; r < 3; ++r) {
    int i = tid + r * 256;
    float x2 = (y[r] - mean) * inv * g2[i] + b2[i];
    z[r] = x2 - xv[r];
    sum2 += z[r];
  }
  float mean2 = block_sum(sum2, sbuf) * (1.f / DD);
  float vs2 = 0.f;
#pragma unroll
  for (int r = 0; r < 3; ++r) { float d = z[r] - mean2; vs2 += d * d; }
  float var2 = block_sum(vs2, sbuf) * (1.f / DD);
  float inv2 = rsqrtf(var2 + 1e-5f);
#pragma unroll
  for (int r = 0; r < 3; ++r) {
    int i = tid + r * 256;
    Out[base + i] = xv[r] + (z[r] - mean2) * inv2 * gd[i] + bd[i];
  }
}

extern "C" void kernel_launch(void* const* d_in, const int* in_sizes, int n_in,
                              void* d_out, int out_size, void* d_ws, size_t ws_size,
                              hipStream_t stream) {
  const float* x = (const float*)d_in[0];
  const int* ids = (const int*)d_in[1];
  // d_in[2] attention_mask: unused by reference
  const float* Wq = (const float*)d_in[3];
  const float* bq = (const float*)d_in[4];
  const float* Wk = (const float*)d_in[5];
  const float* bk = (const float*)d_in[6];
  const float* Wv = (const float*)d_in[7];
  const float* bv = (const float*)d_in[8];
  const float* Wo = (const float*)d_in[9];
  const float* bo = (const float*)d_in[10];
  const float* ln1g = (const float*)d_in[11];
  const float* ln1b = (const float*)d_in[12];
  const float* W1 = (const float*)d_in[13];
  const float* b1 = (const float*)d_in[14];
  const float* W2 = (const float*)d_in[15];
  const float* b2 = (const float*)d_in[16];
  const float* ln2g = (const float*)d_in[17];
  const float* ln2b = (const float*)d_in[18];
  const float* dng = (const float*)d_in[19];
  const float* dnb = (const float*)d_in[20];
  float* out = (float*)d_out;

  char* ws = (char*)d_ws;
  int* seg = (int*)ws;
  size_t off = 256;
  size_t BUFB = (size_t)BB * SS * DD * sizeof(float);
  float* buf0 = (float*)(ws + off);             // Q, later mha
  float* buf1 = (float*)(ws + off + BUFB);      // K, later x1
  float* buf2 = (float*)(ws + off + 2 * BUFB);  // V, later h1
  float* buf3 = (float*)(ws + off + 3 * BUFB);  // ctx, later t2

  seg_kernel<<<BB, 256, 0, stream>>>(ids, seg);
  copy_x<<<2048, 256, 0, stream>>>(x, out, BB * SS * DD / 4);

  dim3 ggrid(DD / 64, SS / 64, BB);
  gemm_rows<<<ggrid, 256, 0, stream>>>(x, Wq, bq, buf0, seg, 1, 0);
  gemm_rows<<<ggrid, 256, 0, stream>>>(x, Wk, bk, buf1, seg, 0, 0);
  gemm_rows<<<ggrid, 256, 0, stream>>>(x, Wv, bv, buf2, seg, 0, 0);

  attn_kernel<<<dim3(SS, BB), 256, 0, stream>>>(buf0, buf1, buf2, buf3, seg);

  gemm_rows<<<ggrid, 256, 0, stream>>>(buf3, Wo, bo, buf0, seg, 1, 0);
  ln_residual<<<dim3(SS, BB), 256, 0, stream>>>(x, buf0, ln1g, ln1b, buf1, seg);
  gemm_rows<<<ggrid, 256, 0, stream>>>(buf1, W1, b1, buf2, seg, 1, 1);
  gemm_rows<<<ggrid, 256, 0, stream>>>(buf2, W2, b2, buf3, seg, 1, 0);
  ln2_diff_scatter<<<dim3(SS, BB), 256, 0, stream>>>(x, buf1, buf3, ln2g, ln2b, dng, dnb, out, seg);
}

// Round 3
// 666.279 us; speedup vs baseline: 2.4711x; 2.4711x over previous
//
#include <hip/hip_runtime.h>
#include <math.h>

#define BB 4
#define SS 2048
#define DD 768
#define HH 8
#define DHD 96
#define SEP_ID 102

typedef __attribute__((ext_vector_type(8))) short bf16x8;
typedef __attribute__((ext_vector_type(4))) float f32x4;

static __device__ __forceinline__ float gelu_tanh(float x) {
  float x3 = x * x * x;
  float t = tanhf(0.7978845608028654f * (x + 0.044715f * x3));
  return 0.5f * x * (1.0f + t);
}

static __device__ __forceinline__ unsigned short f2bf(float f) {
  unsigned int u = __float_as_uint(f);
  u = (u + 0x7FFF + ((u >> 16) & 1)) >> 16;
  return (unsigned short)u;
}

// ---------------- segment discovery ----------------
__global__ void seg_kernel(const int* __restrict__ ids, int* __restrict__ seg) {
  int b = blockIdx.x;
  const int* row = ids + (size_t)b * SS;
  __shared__ int s1[256], s2[256];
  int m1 = SS, m2 = SS;
  for (int i = threadIdx.x; i < SS; i += 256) {
    if (row[i] == SEP_ID) {
      if (i < m1) { m2 = m1; m1 = i; }
      else if (i < m2) { m2 = i; }
    }
  }
  s1[threadIdx.x] = m1; s2[threadIdx.x] = m2;
  __syncthreads();
  for (int off = 128; off > 0; off >>= 1) {
    if (threadIdx.x < off) {
      int a1 = s1[threadIdx.x], a2 = s2[threadIdx.x];
      int b1 = s1[threadIdx.x + off], b2 = s2[threadIdx.x + off];
      int n1 = min(a1, b1);
      int n2 = min(max(a1, b1), min(a2, b2));
      s1[threadIdx.x] = n1; s2[threadIdx.x] = n2;
    }
    __syncthreads();
  }
  if (threadIdx.x == 0) {
    int first = s1[0], second = s2[0];
    bool has2 = (second < SS);
    int mid = SS / 2;
    int src_end = has2 ? first : mid;
    int hyp_lo = has2 ? (first + 1) : mid;
    int hyp_hi = has2 ? second : (SS - 1);
    int n_src = src_end - 1;
    int n_hyp = hyp_hi - hyp_lo;
    int valid = (n_src > 0 && n_hyp > 0) ? 1 : 0;
    if (!valid) { src_end = 1; hyp_lo = 0; hyp_hi = 0; }
    seg[b * 4 + 0] = src_end;
    seg[b * 4 + 1] = hyp_lo;
    seg[b * 4 + 2] = hyp_hi;
    seg[b * 4 + 3] = valid;
  }
}

// ---------------- out = x ----------------
__global__ void copy_x(const float* __restrict__ x, float* __restrict__ out, int n4) {
  int i = blockIdx.x * blockDim.x + threadIdx.x;
  int stride = gridDim.x * blockDim.x;
  const float4* xi = (const float4*)x;
  float4* oi = (float4*)out;
  for (; i < n4; i += stride) oi[i] = xi[i];
}

// ---------------- row-range GEMM (f32 VALU), optional bf16 store ----------------
template <bool BF16OUT>
__global__ __launch_bounds__(256) void gemm_rows(
    const float* __restrict__ A, const float* __restrict__ W,
    const float* __restrict__ bias, void* __restrict__ Cv,
    const int* __restrict__ seg, int sel, int gelu) {
  int b = blockIdx.z;
  int lo = (sel == 0) ? 1 : seg[b * 4 + 1];
  int hi = (sel == 0) ? seg[b * 4 + 0] : seg[b * 4 + 2];
  int row0 = lo + (int)blockIdx.y * 64;
  if (row0 >= hi) return;
  int col0 = blockIdx.x * 64;

  __shared__ float As[16][68];
  __shared__ float Bs[16][64];
  int tid = threadIdx.x;
  int tx = tid & 15, ty = tid >> 4;
  float acc[4][4] = {};

  int am = tid >> 2, ak = (tid & 3) * 4;
  int bk = tid >> 4, bc = (tid & 15) * 4;
  const float* Arow = A + ((size_t)(b * SS + row0 + am)) * DD;
  bool arow_ok = (row0 + am) < hi;

  for (int k0 = 0; k0 < DD; k0 += 16) {
    float4 av = make_float4(0.f, 0.f, 0.f, 0.f);
    if (arow_ok) av = *(const float4*)(Arow + k0 + ak);
    As[ak + 0][am] = av.x; As[ak + 1][am] = av.y;
    As[ak + 2][am] = av.z; As[ak + 3][am] = av.w;
    float4 bv = *(const float4*)(W + (size_t)(k0 + bk) * DD + col0 + bc);
    *(float4*)&Bs[bk][bc] = bv;
    __syncthreads();
#pragma unroll
    for (int kk = 0; kk < 16; ++kk) {
      float4 a = *(const float4*)&As[kk][ty * 4];
      float4 bq = *(const float4*)&Bs[kk][tx * 4];
      float ar[4] = {a.x, a.y, a.z, a.w};
      float br[4] = {bq.x, bq.y, bq.z, bq.w};
#pragma unroll
      for (int i = 0; i < 4; ++i)
#pragma unroll
        for (int j = 0; j < 4; ++j) acc[i][j] += ar[i] * br[j];
    }
    __syncthreads();
  }
  float bs[4];
#pragma unroll
  for (int j = 0; j < 4; ++j) bs[j] = bias[col0 + tx * 4 + j];
#pragma unroll
  for (int i = 0; i < 4; ++i) {
    int row = row0 + ty * 4 + i;
    if (row < hi) {
      size_t cbase = ((size_t)(b * SS + row)) * DD + col0 + tx * 4;
#pragma unroll
      for (int j = 0; j < 4; ++j) {
        float v = acc[i][j] + bs[j];
        if (gelu) v = gelu_tanh(v);
        if (BF16OUT) ((unsigned short*)Cv)[cbase + j] = f2bf(v);
        else ((float*)Cv)[cbase + j] = v;
      }
    }
  }
}

// ---------------- MFMA flash attention ----------------
// block: 256 thr = 4 waves x 16 queries, one head. grid (32, H, B)
__global__ __launch_bounds__(256) void attn_mfma(
    const unsigned short* __restrict__ Q, const unsigned short* __restrict__ K,
    const unsigned short* __restrict__ V, float* __restrict__ ctx,
    const int* __restrict__ seg) {
  int b = blockIdx.z, h = blockIdx.y;
  int src_hi = seg[b * 4 + 0];
  int hyp_lo = seg[b * 4 + 1], hyp_hi = seg[b * 4 + 2];
  int q0b = hyp_lo + (int)blockIdx.x * 64;
  if (q0b >= hyp_hi) return;

  __shared__ unsigned short vt[2][96 * 64];     // V^T chunk, XOR-swizzled, double-buffered
  __shared__ unsigned short plds[4 * 16 * 64];  // per-wave P, XOR-swizzled

  int tid = threadIdx.x;
  int w = tid >> 6, lane = tid & 63;
  int llo = lane & 15, lhi = lane >> 4;

  // Q fragments: lane holds Q[q0+llo][lhi*8 + 32*df .. +8]; clamp to written rows
  int q0 = q0b + w * 16;
  int qrow = min(q0 + llo, hyp_hi - 1);
  const unsigned short* qbase = Q + ((size_t)(b * SS + qrow)) * DD + h * DHD;
  bf16x8 qf[3];
#pragma unroll
  for (int df = 0; df < 3; ++df)
    qf[df] = *(const bf16x8*)(qbase + df * 32 + lhi * 8);

  f32x4 acc[6];
#pragma unroll
  for (int dt = 0; dt < 6; ++dt) acc[dt] = (f32x4){0.f, 0.f, 0.f, 0.f};
  float m_r[4] = {-1e30f, -1e30f, -1e30f, -1e30f};
  float l_r[4] = {0.f, 0.f, 0.f, 0.f};
  const float rs = 0.1020620726159658f;  // 1/sqrt(96)

  int vk = tid & 63, vdg = tid >> 6;
  int cur = 0;

  for (int k0 = 1; k0 < src_hi; k0 += 64) {
    __syncthreads();  // prior-iter reads done before any restage (defensive w/ dbuf)
    // stage V chunk transposed+swizzled: vt[cur][d*64 + (k ^ ((d&7)<<3))]; clamp to written rows
    {
      int krow = min(k0 + vk, src_hi - 1);
      const unsigned short* vbase = V + ((size_t)(b * SS + krow)) * DD + h * DHD;
#pragma unroll
      for (int i = 0; i < 3; ++i) {
        int d0 = vdg * 8 + 32 * i;
        bf16x8 vv = *(const bf16x8*)(vbase + d0);
#pragma unroll
        for (int j = 0; j < 8; ++j)
          vt[cur][(d0 + j) * 64 + (vk ^ (j << 3))] = (unsigned short)vv[j];
      }
    }
    // S = Q K^T tiles (4 tiles of 16 keys); clamp K reads to written rows
    f32x4 s[4];
#pragma unroll
    for (int t = 0; t < 4; ++t) {
      int krow = min(k0 + t * 16 + llo, src_hi - 1);
      const unsigned short* kbase = K + ((size_t)(b * SS + krow)) * DD + h * DHD;
      f32x4 st = (f32x4){0.f, 0.f, 0.f, 0.f};
#pragma unroll
      for (int df = 0; df < 3; ++df)
        st = __builtin_amdgcn_mfma_f32_16x16x32_bf16(
            qf[df], *(const bf16x8*)(kbase + df * 32 + lhi * 8), st, 0, 0, 0);
      s[t] = st;
    }
    // mask + scale, rowwise online softmax (row q=(lhi*4+r), key col = t*16+llo)
    float mx[4] = {-1e30f, -1e30f, -1e30f, -1e30f};
#pragma unroll
    for (int t = 0; t < 4; ++t) {
      bool kv = (k0 + t * 16 + llo) < src_hi;
#pragma unroll
      for (int r = 0; r < 4; ++r) {
        float sv = kv ? s[t][r] * rs : -1e30f;
        s[t][r] = sv;
        mx[r] = fmaxf(mx[r], sv);
      }
    }
#pragma unroll
    for (int st = 1; st < 16; st <<= 1)
#pragma unroll
      for (int r = 0; r < 4; ++r) mx[r] = fmaxf(mx[r], __shfl_xor(mx[r], st));

    float p[4][4];
#pragma unroll
    for (int r = 0; r < 4; ++r) {
      float mn = fmaxf(m_r[r], mx[r]);
      float sc = __expf(m_r[r] - mn);
      m_r[r] = mn;
      l_r[r] *= sc;
#pragma unroll
      for (int dt = 0; dt < 6; ++dt) acc[dt][r] *= sc;
      float ps = 0.f;
#pragma unroll
      for (int t = 0; t < 4; ++t) {
        bool kv = (k0 + t * 16 + llo) < src_hi;
        float pv = kv ? __expf(s[t][r] - mn) : 0.f;
        p[t][r] = pv;
        ps += pv;
      }
#pragma unroll
      for (int st = 1; st < 16; st <<= 1) ps += __shfl_xor(ps, st);
      l_r[r] += ps;
    }
    // write P to per-wave LDS: plds[w][q*64 + (k ^ ((q&7)<<3))]
    unsigned short* pw = &plds[w * 1024];
#pragma unroll
    for (int t = 0; t < 4; ++t)
#pragma unroll
      for (int r = 0; r < 4; ++r) {
        int qq = lhi * 4 + r, kk = t * 16 + llo;
        pw[qq * 64 + (kk ^ ((qq & 7) << 3))] = f2bf(p[t][r]);
      }
    __syncthreads();  // vt[cur] staged + plds written
    // PV: A = P fragments (lane: q=llo, k=lhi*8+kh*32), B = V^T from vt[cur]
    bf16x8 pa[2];
#pragma unroll
    for (int kh = 0; kh < 2; ++kh) {
      int idx = llo * 64 + ((lhi * 8 + kh * 32) ^ ((llo & 7) << 3));
      pa[kh] = *(const bf16x8*)&pw[idx];
    }
#pragma unroll
    for (int dt = 0; dt < 6; ++dt) {
      int d = dt * 16 + llo;
#pragma unroll
      for (int kh = 0; kh < 2; ++kh) {
        int idx = d * 64 + ((lhi * 8 + kh * 32) ^ ((d & 7) << 3));
        acc[dt] = __builtin_amdgcn_mfma_f32_16x16x32_bf16(
            pa[kh], *(const bf16x8*)&vt[cur][idx], acc[dt], 0, 0, 0);
      }
    }
    cur ^= 1;
  }
  // epilogue: ctx[q][h*96+d] = acc/l  (row q=(lhi*4+r), col d=dt*16+llo)
#pragma unroll
  for (int r = 0; r < 4; ++r) {
    int q = q0 + lhi * 4 + r;
    if (q < hyp_hi) {
      float inv = 1.f / l_r[r];
      float* cp = ctx + ((size_t)(b * SS + q)) * DD + h * DHD;
#pragma unroll
      for (int dt = 0; dt < 6; ++dt) cp[dt * 16 + llo] = acc[dt][r] * inv;
    }
  }
}

// ---------------- block reduction helper ----------------
__device__ __forceinline__ float block_sum(float v, float* sbuf) {
#pragma unroll
  for (int off = 32; off > 0; off >>= 1) v += __shfl_xor(v, off);
  int lane = threadIdx.x & 63, w = threadIdx.x >> 6;
  __syncthreads();
  if (lane == 0) sbuf[w] = v;
  __syncthreads();
  return sbuf[0] + sbuf[1] + sbuf[2] + sbuf[3];
}

// ---------------- x1 = LN(x + mha) over hyp rows ----------------
__global__ __launch_bounds__(256) void ln_residual(
    const float* __restrict__ X, const float* __restrict__ Yin,
    const float* __restrict__ g, const float* __restrict__ bta,
    float* __restrict__ Out, const int* __restrict__ seg) {
  int b = blockIdx.y, row = blockIdx.x;
  if (row < seg[b * 4 + 1] || row >= seg[b * 4 + 2]) return;
  __shared__ float sbuf[4];
  size_t base = ((size_t)(b * SS + row)) * DD;
  int tid = threadIdx.x;
  float v[3];
  float sum = 0.f;
#pragma unroll
  for (int r = 0; r < 3; ++r) {
    int i = tid + r * 256;
    v[r] = X[base + i] + Yin[base + i];
    sum += v[r];
  }
  float mean = block_sum(sum, sbuf) * (1.f / DD);
  float vs = 0.f;
#pragma unroll
  for (int r = 0; r < 3; ++r) { float d = v[r] - mean; vs += d * d; }
  float var = block_sum(vs, sbuf) * (1.f / DD);
  float inv = rsqrtf(var + 1e-5f);
#pragma unroll
  for (int r = 0; r < 3; ++r) {
    int i = tid + r * 256;
    Out[base + i] = (v[r] - mean) * inv * g[i] + bta[i];
  }
}

// ---------------- x2 = LN(x1 + t2); diff = LN(x2 - x); out = x + diff ----------------
__global__ __launch_bounds__(256) void ln2_diff_scatter(
    const float* __restrict__ X, const float* __restrict__ X1, const float* __restrict__ T2,
    const float* __restrict__ g2, const float* __restrict__ b2,
    const float* __restrict__ gd, const float* __restrict__ bd,
    float* __restrict__ Out, const int* __restrict__ seg) {
  int b = blockIdx.y, row = blockIdx.x;
  if (row < seg[b * 4 + 1] || row >= seg[b * 4 + 2]) return;
  __shared__ float sbuf[4];
  size_t base = ((size_t)(b * SS + row)) * DD;
  int tid = threadIdx.x;
  float y[3], xv[3];
  float sum = 0.f;
#pragma unroll
  for (int r = 0; r < 3; ++r) {
    int i = tid + r * 256;
    y[r] = X1[base + i] + T2[base + i];
    xv[r] = X[base + i];
    sum += y[r];
  }
  float mean = block_sum(sum, sbuf) * (1.f / DD);
  float vs = 0.f;
#pragma unroll
  for (int r = 0; r < 3; ++r) { float d = y[r] - mean; vs += d * d; }
  float var = block_sum(vs, sbuf) * (1.f / DD);
  float inv = rsqrtf(var + 1e-5f);
  float z[3];
  float sum2 = 0.f;
#pragma unroll
  for (int r = 0; r < 3; ++r) {
    int i = tid + r * 256;
    float x2 = (y[r] - mean) * inv * g2[i] + b2[i];
    z[r] = x2 - xv[r];
    sum2 += z[r];
  }
  float mean2 = block_sum(sum2, sbuf) * (1.f / DD);
  float vs2 = 0.f;
#pragma unroll
  for (int r = 0; r < 3; ++r) { float d = z[r] - mean2; vs2 += d * d; }
  float var2 = block_sum(vs2, sbuf) * (1.f / DD);
  float inv2 = rsqrtf(var2 + 1e-5f);
#pragma unroll
  for (int r = 0; r < 3; ++r) {
    int i = tid + r * 256;
    Out[base + i] = xv[r] + (z[r] - mean2) * inv2 * gd[i] + bd[i];
  }
}

extern "C" void kernel_launch(void* const* d_in, const int* in_sizes, int n_in,
                              void* d_out, int out_size, void* d_ws, size_t ws_size,
                              hipStream_t stream) {
  const float* x = (const float*)d_in[0];
  const int* ids = (const int*)d_in[1];
  const float* Wq = (const float*)d_in[3];
  const float* bq = (const float*)d_in[4];
  const float* Wk = (const float*)d_in[5];
  const float* bk = (const float*)d_in[6];
  const float* Wv = (const float*)d_in[7];
  const float* bv = (const float*)d_in[8];
  const float* Wo = (const float*)d_in[9];
  const float* bo = (const float*)d_in[10];
  const float* ln1g = (const float*)d_in[11];
  const float* ln1b = (const float*)d_in[12];
  const float* W1 = (const float*)d_in[13];
  const float* b1 = (const float*)d_in[14];
  const float* W2 = (const float*)d_in[15];
  const float* b2 = (const float*)d_in[16];
  const float* ln2g = (const float*)d_in[17];
  const float* ln2b = (const float*)d_in[18];
  const float* dng = (const float*)d_in[19];
  const float* dnb = (const float*)d_in[20];
  float* out = (float*)d_out;

  char* ws = (char*)d_ws;
  int* seg = (int*)ws;
  size_t NB = (size_t)BB * SS * DD * sizeof(float);  // 25.2 MB
  char* R1 = ws + 256;
  char* R2 = R1 + NB;
  char* R3 = R2 + NB;
  char* R4 = R3 + NB;
  unsigned short* q_bf = (unsigned short*)R1;
  unsigned short* k_bf = (unsigned short*)(R1 + NB / 2);
  unsigned short* v_bf = (unsigned short*)R2;
  float* ctxb = (float*)R3;
  float* mha = (float*)R4;
  float* x1 = (float*)R1;
  float* h1 = (float*)R2;
  float* t2 = (float*)R3;

  // deterministic contents for any row the segment GEMMs skip
  hipMemsetAsync(R1, 0, NB, stream);
  hipMemsetAsync(R2, 0, NB / 2, stream);

  seg_kernel<<<BB, 256, 0, stream>>>(ids, seg);
  copy_x<<<2048, 256, 0, stream>>>(x, out, BB * SS * DD / 4);

  dim3 ggrid(DD / 64, SS / 64, BB);
  gemm_rows<true><<<ggrid, 256, 0, stream>>>(x, Wq, bq, q_bf, seg, 1, 0);
  gemm_rows<true><<<ggrid, 256, 0, stream>>>(x, Wk, bk, k_bf, seg, 0, 0);
  gemm_rows<true><<<ggrid, 256, 0, stream>>>(x, Wv, bv, v_bf, seg, 0, 0);

  attn_mfma<<<dim3(SS / 64, HH, BB), 256, 0, stream>>>(q_bf, k_bf, v_bf, ctxb, seg);

  gemm_rows<false><<<ggrid, 256, 0, stream>>>(ctxb, Wo, bo, mha, seg, 1, 0);
  ln_residual<<<dim3(SS, BB), 256, 0, stream>>>(x, mha, ln1g, ln1b, x1, seg);
  gemm_rows<false><<<ggrid, 256, 0, stream>>>(x1, W1, b1, h1, seg, 1, 1);
  gemm_rows<false><<<ggrid, 256, 0, stream>>>(h1, W2, b2, t2, seg, 1, 0);
  ln2_diff_scatter<<<dim3(SS, BB), 256, 0, stream>>>(x, x1, t2, ln2g, ln2b, dng, dnb, out, seg);
}

// Round 4
// 556.471 us; speedup vs baseline: 2.9587x; 1.1973x over previous
//
#include <hip/hip_runtime.h>
#include <math.h>

#define BB 4
#define SS 2048
#define DD 768
#define HH 8
#define DHD 96
#define SEP_ID 102

typedef __attribute__((ext_vector_type(8))) short bf16x8;
typedef __attribute__((ext_vector_type(4))) float f32x4;

static __device__ __forceinline__ float gelu_tanh(float x) {
  float x3 = x * x * x;
  float t = tanhf(0.7978845608028654f * (x + 0.044715f * x3));
  return 0.5f * x * (1.0f + t);
}

static __device__ __forceinline__ unsigned short f2bf(float f) {
  unsigned int u = __float_as_uint(f);
  u = (u + 0x7FFF + ((u >> 16) & 1)) >> 16;
  return (unsigned short)u;
}

static __device__ __forceinline__ float bf2f(unsigned short u) {
  return __uint_as_float(((unsigned int)u) << 16);
}

// ---------------- segment discovery ----------------
__global__ void seg_kernel(const int* __restrict__ ids, int* __restrict__ seg) {
  int b = blockIdx.x;
  const int* row = ids + (size_t)b * SS;
  __shared__ int s1[256], s2[256];
  int m1 = SS, m2 = SS;
  for (int i = threadIdx.x; i < SS; i += 256) {
    if (row[i] == SEP_ID) {
      if (i < m1) { m2 = m1; m1 = i; }
      else if (i < m2) { m2 = i; }
    }
  }
  s1[threadIdx.x] = m1; s2[threadIdx.x] = m2;
  __syncthreads();
  for (int off = 128; off > 0; off >>= 1) {
    if (threadIdx.x < off) {
      int a1 = s1[threadIdx.x], a2 = s2[threadIdx.x];
      int b1 = s1[threadIdx.x + off], b2 = s2[threadIdx.x + off];
      s1[threadIdx.x] = min(a1, b1);
      s2[threadIdx.x] = min(max(a1, b1), min(a2, b2));
    }
    __syncthreads();
  }
  if (threadIdx.x == 0) {
    int first = s1[0], second = s2[0];
    bool has2 = (second < SS);
    int mid = SS / 2;
    int src_end = has2 ? first : mid;
    int hyp_lo = has2 ? (first + 1) : mid;
    int hyp_hi = has2 ? second : (SS - 1);
    int valid = ((src_end - 1) > 0 && (hyp_hi - hyp_lo) > 0) ? 1 : 0;
    if (!valid) { src_end = 1; hyp_lo = 0; hyp_hi = 0; }
    seg[b * 4 + 0] = src_end;
    seg[b * 4 + 1] = hyp_lo;
    seg[b * 4 + 2] = hyp_hi;
    seg[b * 4 + 3] = valid;
  }
}

// ---------------- out = x ----------------
__global__ void copy_x(const float* __restrict__ x, float* __restrict__ out, int n4) {
  int i = blockIdx.x * blockDim.x + threadIdx.x;
  int stride = gridDim.x * blockDim.x;
  const float4* xi = (const float4*)x;
  float4* oi = (float4*)out;
  for (; i < n4; i += stride) oi[i] = xi[i];
}

// ---------------- f32 -> bf16 convert ----------------
__global__ void conv_bf(const float* __restrict__ x, unsigned short* __restrict__ o, int n4) {
  int i = blockIdx.x * blockDim.x + threadIdx.x;
  int stride = gridDim.x * blockDim.x;
  const float4* xi = (const float4*)x;
  for (; i < n4; i += stride) {
    float4 v = xi[i];
    ushort4 r;
    r.x = f2bf(v.x); r.y = f2bf(v.y); r.z = f2bf(v.z); r.w = f2bf(v.w);
    *(ushort4*)(o + (size_t)i * 4) = r;
  }
}

// ---------------- W[k][n] f32 -> Wt[n][k] bf16 ----------------
__global__ __launch_bounds__(256) void wtrans(const float* __restrict__ W,
                                              unsigned short* __restrict__ Wt) {
  __shared__ float t[64][65];
  int k0 = blockIdx.x * 64, n0 = blockIdx.y * 64;
  for (int i = threadIdx.x; i < 4096; i += 256) {
    int kk = i >> 6, nn = i & 63;
    t[kk][nn] = W[(size_t)(k0 + kk) * DD + n0 + nn];
  }
  __syncthreads();
  for (int i = threadIdx.x; i < 4096; i += 256) {
    int nn = i >> 6, kk = i & 63;
    Wt[(size_t)(n0 + nn) * DD + k0 + kk] = f2bf(t[kk][nn]);
  }
}

// ---------------- bf16 MFMA GEMM, LDS-free, row-range ----------------
// C[row][col] = A[row][:] @ Wt[col][:]^T + bias;  OUT: 0=f32, 1=bf16, 2=bf16 transposed (Vt[b][col][row])
template <int OUT>
__global__ __launch_bounds__(256) void gemm_mfma(
    const unsigned short* __restrict__ A, const unsigned short* __restrict__ Wt,
    const float* __restrict__ bias, void* __restrict__ C,
    const int* __restrict__ seg, int sel, int gelu, float oscale) {
  int b = blockIdx.z;
  int lo = (sel == 0) ? 1 : seg[b * 4 + 1];
  int hi = (sel == 0) ? seg[b * 4 + 0] : seg[b * 4 + 2];
  int row0 = lo + (int)blockIdx.y * 64;
  if (row0 >= hi) return;
  int col0 = blockIdx.x * 64;

  int tid = threadIdx.x, w = tid >> 6, lane = tid & 63;
  int llo = lane & 15, lhi = lane >> 4;
  int wr = (w >> 1) * 32, wc = (w & 1) * 32;

  const unsigned short* Ab = A + (size_t)b * SS * DD;
  int r0 = min(row0 + wr + llo, hi - 1);
  int r1 = min(row0 + wr + 16 + llo, hi - 1);
  const unsigned short* a0 = Ab + (size_t)r0 * DD + lhi * 8;
  const unsigned short* a1 = Ab + (size_t)r1 * DD + lhi * 8;
  const unsigned short* b0 = Wt + (size_t)(col0 + wc + llo) * DD + lhi * 8;
  const unsigned short* b1 = Wt + (size_t)(col0 + wc + 16 + llo) * DD + lhi * 8;

  f32x4 acc[2][2];
#pragma unroll
  for (int i = 0; i < 2; ++i)
#pragma unroll
    for (int j = 0; j < 2; ++j) acc[i][j] = (f32x4){0.f, 0.f, 0.f, 0.f};

#pragma unroll 4
  for (int k0 = 0; k0 < DD; k0 += 32) {
    bf16x8 af0 = *(const bf16x8*)(a0 + k0);
    bf16x8 af1 = *(const bf16x8*)(a1 + k0);
    bf16x8 bf0 = *(const bf16x8*)(b0 + k0);
    bf16x8 bf1 = *(const bf16x8*)(b1 + k0);
    acc[0][0] = __builtin_amdgcn_mfma_f32_16x16x32_bf16(af0, bf0, acc[0][0], 0, 0, 0);
    acc[0][1] = __builtin_amdgcn_mfma_f32_16x16x32_bf16(af0, bf1, acc[0][1], 0, 0, 0);
    acc[1][0] = __builtin_amdgcn_mfma_f32_16x16x32_bf16(af1, bf0, acc[1][0], 0, 0, 0);
    acc[1][1] = __builtin_amdgcn_mfma_f32_16x16x32_bf16(af1, bf1, acc[1][1], 0, 0, 0);
  }

#pragma unroll
  for (int mi = 0; mi < 2; ++mi)
#pragma unroll
    for (int ni = 0; ni < 2; ++ni) {
      int col = col0 + wc + ni * 16 + llo;
      float bsv = bias[col];
      int rowb = row0 + wr + mi * 16 + lhi * 4;
#pragma unroll
      for (int r = 0; r < 4; ++r) {
        int row = rowb + r;
        if (row < hi) {
          float v = (acc[mi][ni][r] + bsv) * oscale;
          if (gelu) v = gelu_tanh(v);
          if (OUT == 0)
            ((float*)C)[((size_t)(b * SS + row)) * DD + col] = v;
          else if (OUT == 1)
            ((unsigned short*)C)[((size_t)(b * SS + row)) * DD + col] = f2bf(v);
          else
            ((unsigned short*)C)[((size_t)b * DD + col) * SS + row] = f2bf(v);
        }
      }
    }
}

// ---------------- MFMA flash attention, 1 wave/block, barrier-free ----------------
// grid (SS/16, H, B), block 64. Q pre-scaled by 1/sqrt(Dh). V^T in Vt[b][d][key].
__global__ __launch_bounds__(64) void attn_mfma(
    const unsigned short* __restrict__ Q, const unsigned short* __restrict__ K,
    const unsigned short* __restrict__ Vt, unsigned short* __restrict__ ctx,
    const int* __restrict__ seg) {
  int b = blockIdx.z, h = blockIdx.y;
  int src_hi = seg[b * 4 + 0];
  int hyp_lo = seg[b * 4 + 1], hyp_hi = seg[b * 4 + 2];
  int q0 = hyp_lo + (int)blockIdx.x * 16;
  if (q0 >= hyp_hi) return;

  __shared__ unsigned short plds[16 * 64];  // P tile, XOR-swizzled

  int lane = threadIdx.x;
  int llo = lane & 15, lhi = lane >> 4;

  int qrow = min(q0 + llo, hyp_hi - 1);
  const unsigned short* qbase = Q + ((size_t)(b * SS + qrow)) * DD + h * DHD;
  bf16x8 qf[3];
#pragma unroll
  for (int df = 0; df < 3; ++df)
    qf[df] = *(const bf16x8*)(qbase + df * 32 + lhi * 8);

  const unsigned short* Kb = K + (size_t)b * SS * DD + h * DHD;
  const unsigned short* Vb = Vt + ((size_t)b * DD + h * DHD) * SS;

  f32x4 acc[6];
#pragma unroll
  for (int dt = 0; dt < 6; ++dt) acc[dt] = (f32x4){0.f, 0.f, 0.f, 0.f};
  float m_r[4] = {-1e30f, -1e30f, -1e30f, -1e30f};
  float l_r[4] = {0.f, 0.f, 0.f, 0.f};

  for (int k0 = 1; k0 < src_hi; k0 += 64) {
    // S = Q K^T (4 tiles of 16 keys), K fragments direct from global
    f32x4 s[4];
#pragma unroll
    for (int t = 0; t < 4; ++t) {
      int krow = min(k0 + t * 16 + llo, src_hi - 1);
      const unsigned short* kbase = Kb + (size_t)krow * DD;
      f32x4 st = (f32x4){0.f, 0.f, 0.f, 0.f};
#pragma unroll
      for (int df = 0; df < 3; ++df)
        st = __builtin_amdgcn_mfma_f32_16x16x32_bf16(
            qf[df], *(const bf16x8*)(kbase + df * 32 + lhi * 8), st, 0, 0, 0);
      s[t] = st;
    }
    // online softmax: row q=(lhi*4+r), key col = t*16+llo
    float mx[4] = {-1e30f, -1e30f, -1e30f, -1e30f};
#pragma unroll
    for (int t = 0; t < 4; ++t) {
      bool kv = (k0 + t * 16 + llo) < src_hi;
#pragma unroll
      for (int r = 0; r < 4; ++r) {
        float sv = kv ? s[t][r] : -1e30f;
        s[t][r] = sv;
        mx[r] = fmaxf(mx[r], sv);
      }
    }
#pragma unroll
    for (int st = 1; st < 16; st <<= 1)
#pragma unroll
      for (int r = 0; r < 4; ++r) mx[r] = fmaxf(mx[r], __shfl_xor(mx[r], st));

    float p[4][4];
#pragma unroll
    for (int r = 0; r < 4; ++r) {
      float mn = fmaxf(m_r[r], mx[r]);
      float sc = __expf(m_r[r] - mn);
      m_r[r] = mn;
      l_r[r] *= sc;
#pragma unroll
      for (int dt = 0; dt < 6; ++dt) acc[dt][r] *= sc;
      float ps = 0.f;
#pragma unroll
      for (int t = 0; t < 4; ++t) {
        float pv = (s[t][r] > -1e29f) ? __expf(s[t][r] - mn) : 0.f;
        p[t][r] = pv;
        ps += pv;
      }
#pragma unroll
      for (int st = 1; st < 16; st <<= 1) ps += __shfl_xor(ps, st);
      l_r[r] += ps;
    }
    // P -> LDS (wave-private, no barrier): plds[q*64 + (k ^ ((q&7)<<3))]
#pragma unroll
    for (int t = 0; t < 4; ++t)
#pragma unroll
      for (int r = 0; r < 4; ++r) {
        int qq = lhi * 4 + r, kk = t * 16 + llo;
        plds[qq * 64 + (kk ^ ((qq & 7) << 3))] = f2bf(p[t][r]);
      }
    // PV: A = P fragments, B = V^T fragments direct from global
    bf16x8 pa[2];
#pragma unroll
    for (int kh = 0; kh < 2; ++kh) {
      int idx = llo * 64 + ((lhi * 8 + kh * 32) ^ ((llo & 7) << 3));
      pa[kh] = *(const bf16x8*)&plds[idx];
    }
#pragma unroll
    for (int dt = 0; dt < 6; ++dt) {
      const unsigned short* vrow = Vb + (size_t)(dt * 16 + llo) * SS + k0 + lhi * 8;
#pragma unroll
      for (int kh = 0; kh < 2; ++kh) {
        acc[dt] = __builtin_amdgcn_mfma_f32_16x16x32_bf16(
            pa[kh], *(const bf16x8*)(vrow + kh * 32), acc[dt], 0, 0, 0);
      }
    }
  }
  // epilogue -> ctx bf16
#pragma unroll
  for (int r = 0; r < 4; ++r) {
    int q = q0 + lhi * 4 + r;
    if (q < hyp_hi) {
      float inv = 1.f / l_r[r];
      unsigned short* cp = ctx + ((size_t)(b * SS + q)) * DD + h * DHD;
#pragma unroll
      for (int dt = 0; dt < 6; ++dt) cp[dt * 16 + llo] = f2bf(acc[dt][r] * inv);
    }
  }
}

// ---------------- block reduction helper ----------------
__device__ __forceinline__ float block_sum(float v, float* sbuf) {
#pragma unroll
  for (int off = 32; off > 0; off >>= 1) v += __shfl_xor(v, off);
  int lane = threadIdx.x & 63, w = threadIdx.x >> 6;
  __syncthreads();
  if (lane == 0) sbuf[w] = v;
  __syncthreads();
  return sbuf[0] + sbuf[1] + sbuf[2] + sbuf[3];
}

// ---------------- x1 = LN(x + mha) over hyp rows; dual f32/bf16 out ----------------
__global__ __launch_bounds__(256) void ln_residual(
    const float* __restrict__ X, const unsigned short* __restrict__ Yin,
    const float* __restrict__ g, const float* __restrict__ bta,
    float* __restrict__ Out, unsigned short* __restrict__ OutBf,
    const int* __restrict__ seg) {
  int b = blockIdx.y, row = blockIdx.x;
  if (row < seg[b * 4 + 1] || row >= seg[b * 4 + 2]) return;
  __shared__ float sbuf[4];
  size_t base = ((size_t)(b * SS + row)) * DD;
  int tid = threadIdx.x;
  float v[3];
  float sum = 0.f;
#pragma unroll
  for (int r = 0; r < 3; ++r) {
    int i = tid + r * 256;
    v[r] = X[base + i] + bf2f(Yin[base + i]);
    sum += v[r];
  }
  float mean = block_sum(sum, sbuf) * (1.f / DD);
  float vs = 0.f;
#pragma unroll
  for (int r = 0; r < 3; ++r) { float d = v[r] - mean; vs += d * d; }
  float var = block_sum(vs, sbuf) * (1.f / DD);
  float inv = rsqrtf(var + 1e-5f);
#pragma unroll
  for (int r = 0; r < 3; ++r) {
    int i = tid + r * 256;
    float o = (v[r] - mean) * inv * g[i] + bta[i];
    Out[base + i] = o;
    OutBf[base + i] = f2bf(o);
  }
}

// ---------------- x2 = LN(x1 + t2); diff = LN(x2 - x); out = x + diff ----------------
__global__ __launch_bounds__(256) void ln2_diff_scatter(
    const float* __restrict__ X, const float* __restrict__ X1,
    const unsigned short* __restrict__ T2,
    const float* __restrict__ g2, const float* __restrict__ b2,
    const float* __restrict__ gd, const float* __restrict__ bd,
    float* __restrict__ Out, const int* __restrict__ seg) {
  int b = blockIdx.y, row = blockIdx.x;
  if (row < seg[b * 4 + 1] || row >= seg[b * 4 + 2]) return;
  __shared__ float sbuf[4];
  size_t base = ((size_t)(b * SS + row)) * DD;
  int tid = threadIdx.x;
  float y[3], xv[3];
  float sum = 0.f;
#pragma unroll
  for (int r = 0; r < 3; ++r) {
    int i = tid + r * 256;
    y[r] = X1[base + i] + bf2f(T2[base + i]);
    xv[r] = X[base + i];
    sum += y[r];
  }
  float mean = block_sum(sum, sbuf) * (1.f / DD);
  float vs = 0.f;
#pragma unroll
  for (int r = 0; r < 3; ++r) { float d = y[r] - mean; vs += d * d; }
  float var = block_sum(vs, sbuf) * (1.f / DD);
  float inv = rsqrtf(var + 1e-5f);
  float z[3];
  float sum2 = 0.f;
#pragma unroll
  for (int r = 0; r < 3; ++r) {
    int i = tid + r * 256;
    float x2 = (y[r] - mean) * inv * g2[i] + b2[i];
    z[r] = x2 - xv[r];
    sum2 += z[r];
  }
  float mean2 = block_sum(sum2, sbuf) * (1.f / DD);
  float vs2 = 0.f;
#pragma unroll
  for (int r = 0; r < 3; ++r) { float d = z[r] - mean2; vs2 += d * d; }
  float var2 = block_sum(vs2, sbuf) * (1.f / DD);
  float inv2 = rsqrtf(var2 + 1e-5f);
#pragma unroll
  for (int r = 0; r < 3; ++r) {
    int i = tid + r * 256;
    Out[base + i] = xv[r] + (z[r] - mean2) * inv2 * gd[i] + bd[i];
  }
}

extern "C" void kernel_launch(void* const* d_in, const int* in_sizes, int n_in,
                              void* d_out, int out_size, void* d_ws, size_t ws_size,
                              hipStream_t stream) {
  const float* x = (const float*)d_in[0];
  const int* ids = (const int*)d_in[1];
  const float* Wq = (const float*)d_in[3];
  const float* bq = (const float*)d_in[4];
  const float* Wk = (const float*)d_in[5];
  const float* bk = (const float*)d_in[6];
  const float* Wv = (const float*)d_in[7];
  const float* bv = (const float*)d_in[8];
  const float* Wo = (const float*)d_in[9];
  const float* bo = (const float*)d_in[10];
  const float* ln1g = (const float*)d_in[11];
  const float* ln1b = (const float*)d_in[12];
  const float* W1 = (const float*)d_in[13];
  const float* b1 = (const float*)d_in[14];
  const float* W2 = (const float*)d_in[15];
  const float* b2 = (const float*)d_in[16];
  const float* ln2g = (const float*)d_in[17];
  const float* ln2b = (const float*)d_in[18];
  const float* dng = (const float*)d_in[19];
  const float* dnb = (const float*)d_in[20];
  float* out = (float*)d_out;

  char* ws = (char*)d_ws;
  int* seg = (int*)ws;
  size_t NBH = (size_t)BB * SS * DD * 2;  // 12.6 MB (bf16 activation)
  char* Ap = ws + 256;
  char* Bp = Ap + NBH;
  char* Cp = Bp + NBH;
  char* Dp = Cp + NBH;
  char* Fp = Dp + NBH + 8192;             // pad after Vt for fragment tail reads
  char* Gp = Fp + (size_t)BB * SS * DD * 4;

  unsigned short* x_bf = (unsigned short*)Ap;   // -> ctx_bf -> h1_bf
  unsigned short* ctx_bf = (unsigned short*)Ap;
  unsigned short* h1_bf = (unsigned short*)Ap;
  unsigned short* q_bf = (unsigned short*)Bp;   // -> mha_bf
  unsigned short* mha_bf = (unsigned short*)Bp;
  unsigned short* k_bf = (unsigned short*)Cp;   // -> t2_bf
  unsigned short* t2_bf = (unsigned short*)Cp;
  unsigned short* vt_bf = (unsigned short*)Dp;  // -> x1_bf
  unsigned short* x1_bf = (unsigned short*)Dp;
  float* x1f = (float*)Fp;
  unsigned short* wt = (unsigned short*)Gp;     // 6 x 768x768 bf16
  const size_t WSZ = (size_t)DD * DD;

  const float rs = 0.1020620726159658f;  // 1/sqrt(96)

  seg_kernel<<<BB, 256, 0, stream>>>(ids, seg);
  copy_x<<<2048, 256, 0, stream>>>(x, out, BB * SS * DD / 4);
  conv_bf<<<1536, 256, 0, stream>>>(x, x_bf, BB * SS * DD / 4);

  dim3 wgrid(DD / 64, DD / 64);
  wtrans<<<wgrid, 256, 0, stream>>>(Wq, wt + 0 * WSZ);
  wtrans<<<wgrid, 256, 0, stream>>>(Wk, wt + 1 * WSZ);
  wtrans<<<wgrid, 256, 0, stream>>>(Wv, wt + 2 * WSZ);
  wtrans<<<wgrid, 256, 0, stream>>>(Wo, wt + 3 * WSZ);
  wtrans<<<wgrid, 256, 0, stream>>>(W1, wt + 4 * WSZ);
  wtrans<<<wgrid, 256, 0, stream>>>(W2, wt + 5 * WSZ);

  hipMemsetAsync(Dp, 0, NBH + 8192, stream);  // Vt zero (tail fragment reads)

  dim3 ggrid(DD / 64, SS / 64, BB);
  gemm_mfma<1><<<ggrid, 256, 0, stream>>>(x_bf, wt + 0 * WSZ, bq, q_bf, seg, 1, 0, rs);
  gemm_mfma<1><<<ggrid, 256, 0, stream>>>(x_bf, wt + 1 * WSZ, bk, k_bf, seg, 0, 0, 1.f);
  gemm_mfma<2><<<ggrid, 256, 0, stream>>>(x_bf, wt + 2 * WSZ, bv, vt_bf, seg, 0, 0, 1.f);

  attn_mfma<<<dim3(SS / 16, HH, BB), 64, 0, stream>>>(q_bf, k_bf, vt_bf, ctx_bf, seg);

  gemm_mfma<1><<<ggrid, 256, 0, stream>>>(ctx_bf, wt + 3 * WSZ, bo, mha_bf, seg, 1, 0, 1.f);
  ln_residual<<<dim3(SS, BB), 256, 0, stream>>>(x, mha_bf, ln1g, ln1b, x1f, x1_bf, seg);
  gemm_mfma<1><<<ggrid, 256, 0, stream>>>(x1_bf, wt + 4 * WSZ, b1, h1_bf, seg, 1, 1, 1.f);
  gemm_mfma<1><<<ggrid, 256, 0, stream>>>(h1_bf, wt + 5 * WSZ, b2, t2_bf, seg, 1, 0, 1.f);
  ln2_diff_scatter<<<dim3(SS, BB), 256, 0, stream>>>(x, x1f, t2_bf, ln2g, ln2b, dng, dnb, out, seg);
}

// Round 5
// 363.758 us; speedup vs baseline: 4.5261x; 1.5298x over previous
//
#include <hip/hip_runtime.h>
#include <math.h>

#define BB 4
#define SS 2048
#define DD 768
#define HH 8
#define DHD 96
#define SEP_ID 102
#define CHUNK 192
#define NCH_MAX 4
#define QT_MAX 44

typedef __attribute__((ext_vector_type(8))) short bf16x8;
typedef __attribute__((ext_vector_type(4))) float f32x4;

static __device__ __forceinline__ float gelu_tanh(float x) {
  float x3 = x * x * x;
  float t = tanhf(0.7978845608028654f * (x + 0.044715f * x3));
  return 0.5f * x * (1.0f + t);
}

static __device__ __forceinline__ unsigned short f2bf(float f) {
  unsigned int u = __float_as_uint(f);
  u = (u + 0x7FFF + ((u >> 16) & 1)) >> 16;
  return (unsigned short)u;
}

static __device__ __forceinline__ float bf2f(unsigned short u) {
  return __uint_as_float(((unsigned int)u) << 16);
}

// ---------------- segment discovery ----------------
__global__ void seg_kernel(const int* __restrict__ ids, int* __restrict__ seg) {
  int b = blockIdx.x;
  const int* row = ids + (size_t)b * SS;
  __shared__ int s1[256], s2[256];
  int m1 = SS, m2 = SS;
  for (int i = threadIdx.x; i < SS; i += 256) {
    if (row[i] == SEP_ID) {
      if (i < m1) { m2 = m1; m1 = i; }
      else if (i < m2) { m2 = i; }
    }
  }
  s1[threadIdx.x] = m1; s2[threadIdx.x] = m2;
  __syncthreads();
  for (int off = 128; off > 0; off >>= 1) {
    if (threadIdx.x < off) {
      int a1 = s1[threadIdx.x], a2 = s2[threadIdx.x];
      int b1 = s1[threadIdx.x + off], b2 = s2[threadIdx.x + off];
      s1[threadIdx.x] = min(a1, b1);
      s2[threadIdx.x] = min(max(a1, b1), min(a2, b2));
    }
    __syncthreads();
  }
  if (threadIdx.x == 0) {
    int first = s1[0], second = s2[0];
    bool has2 = (second < SS);
    int mid = SS / 2;
    int src_end = has2 ? first : mid;
    int hyp_lo = has2 ? (first + 1) : mid;
    int hyp_hi = has2 ? second : (SS - 1);
    int valid = ((src_end - 1) > 0 && (hyp_hi - hyp_lo) > 0) ? 1 : 0;
    if (!valid) { src_end = 1; hyp_lo = 0; hyp_hi = 0; }
    seg[b * 4 + 0] = src_end;
    seg[b * 4 + 1] = hyp_lo;
    seg[b * 4 + 2] = hyp_hi;
    seg[b * 4 + 3] = valid;
  }
}

// ---------------- out = x ; x_bf = bf16(x) ----------------
__global__ void copyconv(const float* __restrict__ x, float* __restrict__ out,
                         unsigned short* __restrict__ xbf, int n4) {
  int i = blockIdx.x * blockDim.x + threadIdx.x;
  int stride = gridDim.x * blockDim.x;
  const float4* xi = (const float4*)x;
  float4* oi = (float4*)out;
  for (; i < n4; i += stride) {
    float4 v = xi[i];
    oi[i] = v;
    ushort4 r;
    r.x = f2bf(v.x); r.y = f2bf(v.y); r.z = f2bf(v.z); r.w = f2bf(v.w);
    *(ushort4*)(xbf + (size_t)i * 4) = r;
  }
}

// ---------------- 6x W[k][n] f32 -> Wt[n][k] bf16 ----------------
__global__ __launch_bounds__(256) void wtrans6(
    const float* __restrict__ W0, const float* __restrict__ W1,
    const float* __restrict__ W2, const float* __restrict__ W3,
    const float* __restrict__ W4, const float* __restrict__ W5,
    unsigned short* __restrict__ Wt) {
  int z = blockIdx.z;
  const float* W = (z == 0) ? W0 : (z == 1) ? W1 : (z == 2) ? W2
                  : (z == 3) ? W3 : (z == 4) ? W4 : W5;
  unsigned short* O = Wt + (size_t)z * DD * DD;
  __shared__ float t[64][65];
  int k0 = blockIdx.x * 64, n0 = blockIdx.y * 64;
  for (int i = threadIdx.x; i < 4096; i += 256) {
    int kk = i >> 6, nn = i & 63;
    t[kk][nn] = W[(size_t)(k0 + kk) * DD + n0 + nn];
  }
  __syncthreads();
  for (int i = threadIdx.x; i < 4096; i += 256) {
    int nn = i >> 6, kk = i & 63;
    O[(size_t)(n0 + nn) * DD + k0 + kk] = f2bf(t[kk][nn]);
  }
}

#define MFMA16(A, B, C) __builtin_amdgcn_mfma_f32_16x16x32_bf16(A, B, C, 0, 0, 0)

// ---------------- fused QKV GEMM (bf16 MFMA, LDS-free, reg prefetch) ----------------
// grid (36, 11, BB): x/12 selects {Q,K,V}; Q over hyp rows (scaled rs), K/V over src rows; V stored transposed
__global__ __launch_bounds__(256) void gemm_qkv(
    const unsigned short* __restrict__ A, const unsigned short* __restrict__ Wt3,
    const float* __restrict__ bq, const float* __restrict__ bk, const float* __restrict__ bv,
    unsigned short* __restrict__ Qo, unsigned short* __restrict__ Ko,
    unsigned short* __restrict__ Vto, const int* __restrict__ seg, float rs) {
  int b = blockIdx.z;
  int which = blockIdx.x / 12;
  int col0 = (blockIdx.x % 12) * 64;
  int lo = (which == 0) ? seg[b * 4 + 1] : 1;
  int hi = (which == 0) ? seg[b * 4 + 2] : seg[b * 4 + 0];
  int row0 = lo + (int)blockIdx.y * 64;
  if (row0 >= hi) return;

  const unsigned short* Wt = Wt3 + (size_t)which * DD * DD;
  const float* bias = (which == 0) ? bq : (which == 1) ? bk : bv;

  int tid = threadIdx.x, w = tid >> 6, lane = tid & 63;
  int llo = lane & 15, lhi = lane >> 4;
  int wr = (w >> 1) * 32, wc = (w & 1) * 32;

  const unsigned short* Ab = A + (size_t)b * SS * DD;
  int r0 = min(row0 + wr + llo, hi - 1);
  int r1 = min(row0 + wr + 16 + llo, hi - 1);
  const unsigned short* a0 = Ab + (size_t)r0 * DD + lhi * 8;
  const unsigned short* a1 = Ab + (size_t)r1 * DD + lhi * 8;
  const unsigned short* b0 = Wt + (size_t)(col0 + wc + llo) * DD + lhi * 8;
  const unsigned short* b1 = Wt + (size_t)(col0 + wc + 16 + llo) * DD + lhi * 8;

  f32x4 acc[2][2];
#pragma unroll
  for (int i = 0; i < 2; ++i)
#pragma unroll
    for (int j = 0; j < 2; ++j) acc[i][j] = (f32x4){0.f, 0.f, 0.f, 0.f};

  bf16x8 c0 = *(const bf16x8*)a0, c1 = *(const bf16x8*)a1;
  bf16x8 c2 = *(const bf16x8*)b0, c3 = *(const bf16x8*)b1;
#pragma unroll
  for (int k0 = 0; k0 < DD; k0 += 32) {
    bf16x8 n0, n1, n2, n3;
    if (k0 + 32 < DD) {
      n0 = *(const bf16x8*)(a0 + k0 + 32);
      n1 = *(const bf16x8*)(a1 + k0 + 32);
      n2 = *(const bf16x8*)(b0 + k0 + 32);
      n3 = *(const bf16x8*)(b1 + k0 + 32);
    }
    acc[0][0] = MFMA16(c0, c2, acc[0][0]);
    acc[0][1] = MFMA16(c0, c3, acc[0][1]);
    acc[1][0] = MFMA16(c1, c2, acc[1][0]);
    acc[1][1] = MFMA16(c1, c3, acc[1][1]);
    c0 = n0; c1 = n1; c2 = n2; c3 = n3;
  }

  float osc = (which == 0) ? rs : 1.f;
#pragma unroll
  for (int mi = 0; mi < 2; ++mi)
#pragma unroll
    for (int ni = 0; ni < 2; ++ni) {
      int col = col0 + wc + ni * 16 + llo;
      float bsv = bias[col];
      int rowb = row0 + wr + mi * 16 + lhi * 4;
#pragma unroll
      for (int r = 0; r < 4; ++r) {
        int row = rowb + r;
        if (row < hi) {
          float v = (acc[mi][ni][r] + bsv) * osc;
          if (which == 2)
            Vto[((size_t)b * DD + col) * SS + row] = f2bf(v);
          else if (which == 1)
            Ko[((size_t)(b * SS + row)) * DD + col] = f2bf(v);
          else
            Qo[((size_t)(b * SS + row)) * DD + col] = f2bf(v);
        }
      }
    }
}

// ---------------- generic bf16 MFMA GEMM over hyp rows, reg prefetch ----------------
__global__ __launch_bounds__(256) void gemm_mfma(
    const unsigned short* __restrict__ A, const unsigned short* __restrict__ Wt,
    const float* __restrict__ bias, unsigned short* __restrict__ C,
    const int* __restrict__ seg, int gelu) {
  int b = blockIdx.z;
  int lo = seg[b * 4 + 1], hi = seg[b * 4 + 2];
  int row0 = lo + (int)blockIdx.y * 64;
  if (row0 >= hi) return;
  int col0 = blockIdx.x * 64;

  int tid = threadIdx.x, w = tid >> 6, lane = tid & 63;
  int llo = lane & 15, lhi = lane >> 4;
  int wr = (w >> 1) * 32, wc = (w & 1) * 32;

  const unsigned short* Ab = A + (size_t)b * SS * DD;
  int r0 = min(row0 + wr + llo, hi - 1);
  int r1 = min(row0 + wr + 16 + llo, hi - 1);
  const unsigned short* a0 = Ab + (size_t)r0 * DD + lhi * 8;
  const unsigned short* a1 = Ab + (size_t)r1 * DD + lhi * 8;
  const unsigned short* b0 = Wt + (size_t)(col0 + wc + llo) * DD + lhi * 8;
  const unsigned short* b1 = Wt + (size_t)(col0 + wc + 16 + llo) * DD + lhi * 8;

  f32x4 acc[2][2];
#pragma unroll
  for (int i = 0; i < 2; ++i)
#pragma unroll
    for (int j = 0; j < 2; ++j) acc[i][j] = (f32x4){0.f, 0.f, 0.f, 0.f};

  bf16x8 c0 = *(const bf16x8*)a0, c1 = *(const bf16x8*)a1;
  bf16x8 c2 = *(const bf16x8*)b0, c3 = *(const bf16x8*)b1;
#pragma unroll
  for (int k0 = 0; k0 < DD; k0 += 32) {
    bf16x8 n0, n1, n2, n3;
    if (k0 + 32 < DD) {
      n0 = *(const bf16x8*)(a0 + k0 + 32);
      n1 = *(const bf16x8*)(a1 + k0 + 32);
      n2 = *(const bf16x8*)(b0 + k0 + 32);
      n3 = *(const bf16x8*)(b1 + k0 + 32);
    }
    acc[0][0] = MFMA16(c0, c2, acc[0][0]);
    acc[0][1] = MFMA16(c0, c3, acc[0][1]);
    acc[1][0] = MFMA16(c1, c2, acc[1][0]);
    acc[1][1] = MFMA16(c1, c3, acc[1][1]);
    c0 = n0; c1 = n1; c2 = n2; c3 = n3;
  }

#pragma unroll
  for (int mi = 0; mi < 2; ++mi)
#pragma unroll
    for (int ni = 0; ni < 2; ++ni) {
      int col = col0 + wc + ni * 16 + llo;
      float bsv = bias[col];
      int rowb = row0 + wr + mi * 16 + lhi * 4;
#pragma unroll
      for (int r = 0; r < 4; ++r) {
        int row = rowb + r;
        if (row < hi) {
          float v = acc[mi][ni][r] + bsv;
          if (gelu) v = gelu_tanh(v);
          C[((size_t)(b * SS + row)) * DD + col] = f2bf(v);
        }
      }
    }
}

// ---------------- split-K flash attention: partials ----------------
// grid (QT_MAX, NCH_MAX, 32), block 64. slot = 3072B bf16 acc[16][96] + 64B m[16] + 64B l[16]
__global__ __launch_bounds__(64) void attn_split(
    const unsigned short* __restrict__ Q, const unsigned short* __restrict__ K,
    const unsigned short* __restrict__ Vt, char* __restrict__ part,
    const int* __restrict__ seg) {
  int bh = blockIdx.z;
  int b = bh >> 3, h = bh & 7;
  int src_hi = seg[b * 4 + 0];
  int hyp_lo = seg[b * 4 + 1], hyp_hi = seg[b * 4 + 2];
  int q0 = hyp_lo + (int)blockIdx.x * 16;
  if (q0 >= hyp_hi) return;
  int ks = 1 + (int)blockIdx.y * CHUNK;
  if (ks >= src_hi) return;
  int ke = min(ks + CHUNK, src_hi);

  __shared__ unsigned short plds[16 * 64];

  int lane = threadIdx.x;
  int llo = lane & 15, lhi = lane >> 4;

  int qrow = min(q0 + llo, hyp_hi - 1);
  const unsigned short* qbase = Q + ((size_t)(b * SS + qrow)) * DD + h * DHD;
  bf16x8 qf[3];
#pragma unroll
  for (int df = 0; df < 3; ++df)
    qf[df] = *(const bf16x8*)(qbase + df * 32 + lhi * 8);

  const unsigned short* Kb = K + (size_t)b * SS * DD + h * DHD;
  const unsigned short* Vb = Vt + ((size_t)b * DD + h * DHD) * SS;

  f32x4 acc[6];
#pragma unroll
  for (int dt = 0; dt < 6; ++dt) acc[dt] = (f32x4){0.f, 0.f, 0.f, 0.f};
  float m_r[4] = {-1e30f, -1e30f, -1e30f, -1e30f};
  float l_r[4] = {0.f, 0.f, 0.f, 0.f};

  for (int k0 = ks; k0 < ke; k0 += 64) {
    f32x4 s[4];
#pragma unroll
    for (int t = 0; t < 4; ++t) {
      int krow = min(k0 + t * 16 + llo, ke - 1);
      const unsigned short* kbase = Kb + (size_t)krow * DD;
      f32x4 st = (f32x4){0.f, 0.f, 0.f, 0.f};
#pragma unroll
      for (int df = 0; df < 3; ++df)
        st = MFMA16(qf[df], *(const bf16x8*)(kbase + df * 32 + lhi * 8), st);
      s[t] = st;
    }
    float mx[4] = {-1e30f, -1e30f, -1e30f, -1e30f};
#pragma unroll
    for (int t = 0; t < 4; ++t) {
      bool kv = (k0 + t * 16 + llo) < ke;
#pragma unroll
      for (int r = 0; r < 4; ++r) {
        float sv = kv ? s[t][r] : -1e30f;
        s[t][r] = sv;
        mx[r] = fmaxf(mx[r], sv);
      }
    }
#pragma unroll
    for (int st = 1; st < 16; st <<= 1)
#pragma unroll
      for (int r = 0; r < 4; ++r) mx[r] = fmaxf(mx[r], __shfl_xor(mx[r], st));

    float p[4][4];
#pragma unroll
    for (int r = 0; r < 4; ++r) {
      float mn = fmaxf(m_r[r], mx[r]);
      float sc = __expf(m_r[r] - mn);
      m_r[r] = mn;
      l_r[r] *= sc;
#pragma unroll
      for (int dt = 0; dt < 6; ++dt) acc[dt][r] *= sc;
      float ps = 0.f;
#pragma unroll
      for (int t = 0; t < 4; ++t) {
        float pv = (s[t][r] > -1e29f) ? __expf(s[t][r] - mn) : 0.f;
        p[t][r] = pv;
        ps += pv;
      }
#pragma unroll
      for (int st = 1; st < 16; st <<= 1) ps += __shfl_xor(ps, st);
      l_r[r] += ps;
    }
#pragma unroll
    for (int t = 0; t < 4; ++t)
#pragma unroll
      for (int r = 0; r < 4; ++r) {
        int qq = lhi * 4 + r, kk = t * 16 + llo;
        plds[qq * 64 + (kk ^ ((qq & 7) << 3))] = f2bf(p[t][r]);
      }
    bf16x8 pa[2];
#pragma unroll
    for (int kh = 0; kh < 2; ++kh) {
      int idx = llo * 64 + ((lhi * 8 + kh * 32) ^ ((llo & 7) << 3));
      pa[kh] = *(const bf16x8*)&plds[idx];
    }
#pragma unroll
    for (int dt = 0; dt < 6; ++dt) {
      const unsigned short* vrow = Vb + (size_t)(dt * 16 + llo) * SS + k0 + lhi * 8;
#pragma unroll
      for (int kh = 0; kh < 2; ++kh)
        acc[dt] = MFMA16(pa[kh], *(const bf16x8*)(vrow + kh * 32), acc[dt]);
    }
  }
  // write partial slot
  char* slot = part + (((size_t)bh * QT_MAX + blockIdx.x) * NCH_MAX + blockIdx.y) * 3200;
  unsigned short* pacc = (unsigned short*)slot;
  float* pml = (float*)(slot + 3072);
#pragma unroll
  for (int r = 0; r < 4; ++r) {
    int qq = lhi * 4 + r;
#pragma unroll
    for (int dt = 0; dt < 6; ++dt)
      pacc[qq * 96 + dt * 16 + llo] = f2bf(acc[dt][r]);
    if (llo == 0) { pml[qq] = m_r[r]; pml[16 + qq] = l_r[r]; }
  }
}

// ---------------- split-K reduce -> ctx bf16 ----------------
__global__ __launch_bounds__(128) void attn_reduce(
    const char* __restrict__ part, unsigned short* __restrict__ ctx,
    const int* __restrict__ seg) {
  int bh = blockIdx.y;
  int b = bh >> 3, h = bh & 7;
  int src_hi = seg[b * 4 + 0];
  int hyp_lo = seg[b * 4 + 1], hyp_hi = seg[b * 4 + 2];
  int q0 = hyp_lo + (int)blockIdx.x * 16;
  if (q0 >= hyp_hi) return;
  int nch = (src_hi - 1 + CHUNK - 1) / CHUNK;
  if (nch > NCH_MAX) nch = NCH_MAX;

  __shared__ float ml[NCH_MAX][32];
  __shared__ float Mg[16], invL[16], sc[NCH_MAX][16];
  int tid = threadIdx.x;
  const char* base = part + ((size_t)bh * QT_MAX + blockIdx.x) * NCH_MAX * 3200;
  if (tid < 32 * nch) {
    int c = tid >> 5, i = tid & 31;
    ml[c][i] = ((const float*)(base + c * 3200 + 3072))[i];
  }
  __syncthreads();
  if (tid < 16) {
    float mg = -1e30f;
    for (int c = 0; c < nch; ++c) mg = fmaxf(mg, ml[c][tid]);
    float lg = 0.f;
    for (int c = 0; c < nch; ++c) lg += ml[c][16 + tid] * __expf(ml[c][tid] - mg);
    Mg[tid] = mg;
    invL[tid] = 1.f / lg;
  }
  __syncthreads();
  if (tid < 16 * nch) {
    int c = tid >> 4, q = tid & 15;
    sc[c][q] = __expf(ml[c][q] - Mg[q]);
  }
  __syncthreads();
  for (int i = tid; i < 1536; i += 128) {
    int q = i / 96, d = i - q * 96;
    float v = 0.f;
    for (int c = 0; c < nch; ++c)
      v += bf2f(((const unsigned short*)(base + c * 3200))[i]) * sc[c][q];
    int qq = q0 + q;
    if (qq < hyp_hi)
      ctx[((size_t)(b * SS + qq)) * DD + h * DHD + d] = f2bf(v * invL[q]);
  }
}

// ---------------- block reduction helper ----------------
__device__ __forceinline__ float block_sum(float v, float* sbuf) {
#pragma unroll
  for (int off = 32; off > 0; off >>= 1) v += __shfl_xor(v, off);
  int lane = threadIdx.x & 63, w = threadIdx.x >> 6;
  __syncthreads();
  if (lane == 0) sbuf[w] = v;
  __syncthreads();
  return sbuf[0] + sbuf[1] + sbuf[2] + sbuf[3];
}

// ---------------- x1 = LN(x + mha) over hyp rows; dual f32/bf16 out ----------------
__global__ __launch_bounds__(256) void ln_residual(
    const float* __restrict__ X, const unsigned short* __restrict__ Yin,
    const float* __restrict__ g, const float* __restrict__ bta,
    float* __restrict__ Out, unsigned short* __restrict__ OutBf,
    const int* __restrict__ seg) {
  int b = blockIdx.y;
  int row = seg[b * 4 + 1] + (int)blockIdx.x;
  if (row >= seg[b * 4 + 2]) return;
  __shared__ float sbuf[4];
  size_t base = ((size_t)(b * SS + row)) * DD;
  int tid = threadIdx.x;
  float v[3];
  float sum = 0.f;
#pragma unroll
  for (int r = 0; r < 3; ++r) {
    int i = tid + r * 256;
    v[r] = X[base + i] + bf2f(Yin[base + i]);
    sum += v[r];
  }
  float mean = block_sum(sum, sbuf) * (1.f / DD);
  float vs = 0.f;
#pragma unroll
  for (int r = 0; r < 3; ++r) { float d = v[r] - mean; vs += d * d; }
  float var = block_sum(vs, sbuf) * (1.f / DD);
  float inv = rsqrtf(var + 1e-5f);
#pragma unroll
  for (int r = 0; r < 3; ++r) {
    int i = tid + r * 256;
    float o = (v[r] - mean) * inv * g[i] + bta[i];
    Out[base + i] = o;
    OutBf[base + i] = f2bf(o);
  }
}

// ---------------- x2 = LN(x1 + t2); diff = LN(x2 - x); out = x + diff ----------------
__global__ __launch_bounds__(256) void ln2_diff_scatter(
    const float* __restrict__ X, const float* __restrict__ X1,
    const unsigned short* __restrict__ T2,
    const float* __restrict__ g2, const float* __restrict__ b2,
    const float* __restrict__ gd, const float* __restrict__ bd,
    float* __restrict__ Out, const int* __restrict__ seg) {
  int b = blockIdx.y;
  int row = seg[b * 4 + 1] + (int)blockIdx.x;
  if (row >= seg[b * 4 + 2]) return;
  __shared__ float sbuf[4];
  size_t base = ((size_t)(b * SS + row)) * DD;
  int tid = threadIdx.x;
  float y[3], xv[3];
  float sum = 0.f;
#pragma unroll
  for (int r = 0; r < 3; ++r) {
    int i = tid + r * 256;
    y[r] = X1[base + i] + bf2f(T2[base + i]);
    xv[r] = X[base + i];
    sum += y[r];
  }
  float mean = block_sum(sum, sbuf) * (1.f / DD);
  float vs = 0.f;
#pragma unroll
  for (int r = 0; r < 3; ++r) { float d = y[r] - mean; vs += d * d; }
  float var = block_sum(vs, sbuf) * (1.f / DD);
  float inv = rsqrtf(var + 1e-5f);
  float z[3];
  float sum2 = 0.f;
#pragma unroll
  for (int r = 0; r < 3; ++r) {
    int i = tid + r * 256;
    float x2 = (y[r] - mean) * inv * g2[i] + b2[i];
    z[r] = x2 - xv[r];
    sum2 += z[r];
  }
  float mean2 = block_sum(sum2, sbuf) * (1.f / DD);
  float vs2 = 0.f;
#pragma unroll
  for (int r = 0; r < 3; ++r) { float d = z[r] - mean2; vs2 += d * d; }
  float var2 = block_sum(vs2, sbuf) * (1.f / DD);
  float inv2 = rsqrtf(var2 + 1e-5f);
#pragma unroll
  for (int r = 0; r < 3; ++r) {
    int i = tid + r * 256;
    Out[base + i] = xv[r] + (z[r] - mean2) * inv2 * gd[i] + bd[i];
  }
}

extern "C" void kernel_launch(void* const* d_in, const int* in_sizes, int n_in,
                              void* d_out, int out_size, void* d_ws, size_t ws_size,
                              hipStream_t stream) {
  const float* x = (const float*)d_in[0];
  const int* ids = (const int*)d_in[1];
  const float* Wq = (const float*)d_in[3];
  const float* bq = (const float*)d_in[4];
  const float* Wk = (const float*)d_in[5];
  const float* bk = (const float*)d_in[6];
  const float* Wv = (const float*)d_in[7];
  const float* bv = (const float*)d_in[8];
  const float* Wo = (const float*)d_in[9];
  const float* bo = (const float*)d_in[10];
  const float* ln1g = (const float*)d_in[11];
  const float* ln1b = (const float*)d_in[12];
  const float* W1 = (const float*)d_in[13];
  const float* b1 = (const float*)d_in[14];
  const float* W2 = (const float*)d_in[15];
  const float* b2 = (const float*)d_in[16];
  const float* ln2g = (const float*)d_in[17];
  const float* ln2b = (const float*)d_in[18];
  const float* dng = (const float*)d_in[19];
  const float* dnb = (const float*)d_in[20];
  float* out = (float*)d_out;

  char* ws = (char*)d_ws;
  int* seg = (int*)ws;
  size_t NBH = (size_t)BB * SS * DD * 2;  // 12.6 MB bf16
  char* Ap = ws + 256;                    // x_bf -> ctx_bf -> h1_bf
  char* Bp = Ap + NBH;                    // q_bf -> mha_bf
  char* Cp = Bp + NBH;                    // k_bf -> t2_bf
  char* Dp = Cp + NBH;                    // vt_bf -> x1_bf
  char* Fp = Dp + NBH + 8192;             // attn partials -> x1f (f32, 25.2 MB)
  char* Gp = Fp + (size_t)BB * SS * DD * 4;  // wt: 6 x 768x768 bf16

  unsigned short* x_bf = (unsigned short*)Ap;
  unsigned short* ctx_bf = (unsigned short*)Ap;
  unsigned short* h1_bf = (unsigned short*)Ap;
  unsigned short* q_bf = (unsigned short*)Bp;
  unsigned short* mha_bf = (unsigned short*)Bp;
  unsigned short* k_bf = (unsigned short*)Cp;
  unsigned short* t2_bf = (unsigned short*)Cp;
  unsigned short* vt_bf = (unsigned short*)Dp;
  unsigned short* x1_bf = (unsigned short*)Dp;
  char* part = Fp;                        // 32*44*4 slots x 3200 B = 18.0 MB
  float* x1f = (float*)Fp;
  unsigned short* wt = (unsigned short*)Gp;
  const size_t WSZ = (size_t)DD * DD;

  const float rs = 0.1020620726159658f;  // 1/sqrt(96)

  seg_kernel<<<BB, 256, 0, stream>>>(ids, seg);
  copyconv<<<2048, 256, 0, stream>>>(x, out, x_bf, BB * SS * DD / 4);
  wtrans6<<<dim3(DD / 64, DD / 64, 6), 256, 0, stream>>>(Wq, Wk, Wv, Wo, W1, W2, wt);
  hipMemsetAsync(Dp, 0, NBH + 8192, stream);  // Vt zero (PV tail fragment reads)

  gemm_qkv<<<dim3(36, 11, BB), 256, 0, stream>>>(
      x_bf, wt, bq, bk, bv, q_bf, k_bf, vt_bf, seg, rs);

  attn_split<<<dim3(QT_MAX, NCH_MAX, 32), 64, 0, stream>>>(q_bf, k_bf, vt_bf, part, seg);
  attn_reduce<<<dim3(QT_MAX, 32), 128, 0, stream>>>(part, ctx_bf, seg);

  gemm_mfma<<<dim3(12, 11, BB), 256, 0, stream>>>(ctx_bf, wt + 3 * WSZ, bo, mha_bf, seg, 0);
  ln_residual<<<dim3(704, BB), 256, 0, stream>>>(x, mha_bf, ln1g, ln1b, x1f, x1_bf, seg);
  gemm_mfma<<<dim3(12, 11, BB), 256, 0, stream>>>(x1_bf, wt + 4 * WSZ, b1, h1_bf, seg, 1);
  gemm_mfma<<<dim3(12, 11, BB), 256, 0, stream>>>(h1_bf, wt + 5 * WSZ, b2, t2_bf, seg, 0);
  ln2_diff_scatter<<<dim3(704, BB), 256, 0, stream>>>(x, x1f, t2_bf, ln2g, ln2b, dng, dnb, out, seg);
}